// Round 1
// baseline (244.914 us; speedup 1.0000x reference)
//
#include <hip/hip_runtime.h>
#include <hip/hip_bf16.h>
#include <math.h>

#define Bq 8
#define Tq 4096
#define Dq 512
#define Hq 512
#define Mq (Bq * Tq)   // 32768

#define BK 64
#define LDK 72         // padded LDS leading dim (bf16 elems), keeps 16B alignment

#define NC 64          // chunks along T
#define CL 64          // chunk length (NC*CL == Tq)

typedef __bf16 bf16x8 __attribute__((ext_vector_type(8)));
typedef float f32x4 __attribute__((ext_vector_type(4)));

__device__ __forceinline__ unsigned short f2bf(float f) {
    // round-to-nearest-even fp32 -> bf16
    unsigned int u = __float_as_uint(f);
    unsigned int r = u + 0x7fffu + ((u >> 16) & 1u);
    return (unsigned short)(r >> 16);
}

// ---------------- weight conversion fp32 -> bf16 ----------------
__global__ void convert_weights(const float* __restrict__ Wz,
                                const float* __restrict__ Wh,
                                unsigned short* __restrict__ out) {
    int idx = (blockIdx.x * 256 + threadIdx.x) * 8;
    const int half = Dq * Hq;  // 262144
#pragma unroll
    for (int j = 0; j < 8; ++j) {
        int i = idx + j;
        float v = (i < half) ? Wz[i] : Wh[i - half];
        out[i] = f2bf(v);
    }
}

// ---------------- fused dual GEMM + gate epilogue ----------------
// out per element: c = 1 - sigmoid(k), v = sigmoid(k) * g(th)
// k  = x @ Wz^T + bz ; th = x @ Wh^T + bh
__global__ __launch_bounds__(256, 2)
void gemm_fused(const float* __restrict__ x,
                const unsigned short* __restrict__ Wzb,
                const unsigned short* __restrict__ Whb,
                const float* __restrict__ bz,
                const float* __restrict__ bh,
                float* __restrict__ Cc,
                float* __restrict__ Vv) {
    __shared__ unsigned short As[128 * LDK];
    __shared__ unsigned short Bzs[128 * LDK];
    __shared__ unsigned short Bhs[128 * LDK];

    const int tid = threadIdx.x;
    const int lane = tid & 63;
    const int wave = tid >> 6;
    const int wm = (wave >> 1) * 64;   // wave row offset in tile
    const int wn = (wave & 1) * 64;    // wave col offset in tile
    const int mBase = blockIdx.x * 128;
    const int nBase = blockIdx.y * 128;

    f32x4 zero = {0.f, 0.f, 0.f, 0.f};
    f32x4 accz[4][4], acch[4][4];
#pragma unroll
    for (int i = 0; i < 4; ++i)
#pragma unroll
        for (int j = 0; j < 4; ++j) { accz[i][j] = zero; acch[i][j] = zero; }

    const int srow = tid >> 1;          // 0..127
    const int skcol = (tid & 1) * 32;   // 0 or 32

    for (int k0 = 0; k0 < Dq; k0 += BK) {
        // ---- stage A tile (fp32 -> bf16) ----
        {
            const float* src = x + (size_t)(mBase + srow) * Dq + k0 + skcol;
            alignas(16) unsigned short tmp[32];
#pragma unroll
            for (int j = 0; j < 8; ++j) {
                float4 f = reinterpret_cast<const float4*>(src)[j];
                tmp[j * 4 + 0] = f2bf(f.x);
                tmp[j * 4 + 1] = f2bf(f.y);
                tmp[j * 4 + 2] = f2bf(f.z);
                tmp[j * 4 + 3] = f2bf(f.w);
            }
            unsigned short* dst = &As[srow * LDK + skcol];
#pragma unroll
            for (int j = 0; j < 4; ++j)
                reinterpret_cast<uint4*>(dst)[j] = reinterpret_cast<uint4*>(tmp)[j];
        }
        // ---- stage B tiles (bf16 passthrough) ----
        {
            const unsigned short* srcz = Wzb + (size_t)(nBase + srow) * Dq + k0 + skcol;
            const unsigned short* srch = Whb + (size_t)(nBase + srow) * Dq + k0 + skcol;
            unsigned short* dstz = &Bzs[srow * LDK + skcol];
            unsigned short* dsth = &Bhs[srow * LDK + skcol];
#pragma unroll
            for (int j = 0; j < 4; ++j) {
                reinterpret_cast<uint4*>(dstz)[j] = reinterpret_cast<const uint4*>(srcz)[j];
                reinterpret_cast<uint4*>(dsth)[j] = reinterpret_cast<const uint4*>(srch)[j];
            }
        }
        __syncthreads();

#pragma unroll
        for (int ks = 0; ks < BK; ks += 32) {
            const int kidx = ks + (lane >> 4) * 8;
            bf16x8 af[4], bzf[4], bhf[4];
#pragma unroll
            for (int i = 0; i < 4; ++i) {
                int row = wm + i * 16 + (lane & 15);
                af[i] = *reinterpret_cast<const bf16x8*>(&As[row * LDK + kidx]);
            }
#pragma unroll
            for (int i = 0; i < 4; ++i) {
                int row = wn + i * 16 + (lane & 15);
                bzf[i] = *reinterpret_cast<const bf16x8*>(&Bzs[row * LDK + kidx]);
                bhf[i] = *reinterpret_cast<const bf16x8*>(&Bhs[row * LDK + kidx]);
            }
#pragma unroll
            for (int mi = 0; mi < 4; ++mi)
#pragma unroll
                for (int ni = 0; ni < 4; ++ni) {
                    accz[mi][ni] = __builtin_amdgcn_mfma_f32_16x16x32_bf16(
                        af[mi], bzf[ni], accz[mi][ni], 0, 0, 0);
                    acch[mi][ni] = __builtin_amdgcn_mfma_f32_16x16x32_bf16(
                        af[mi], bhf[ni], acch[mi][ni], 0, 0, 0);
                }
        }
        __syncthreads();
    }

    // ---- epilogue: C/D layout col=lane&15, row=(lane>>4)*4+reg ----
    const int colL = lane & 15;
    const int rowQ = (lane >> 4) * 4;
#pragma unroll
    for (int mi = 0; mi < 4; ++mi) {
#pragma unroll
        for (int ni = 0; ni < 4; ++ni) {
            int h = nBase + wn + ni * 16 + colL;
            float bzv = bz[h];
            float bhv = bh[h];
#pragma unroll
            for (int r = 0; r < 4; ++r) {
                int bt = mBase + wm + mi * 16 + rowQ + r;
                float kv = accz[mi][ni][r] + bzv;
                float th = acch[mi][ni][r] + bhv;
                float c = 1.0f / (1.0f + __expf(kv));    // 1 - sigmoid(k)
                float z = 1.0f / (1.0f + __expf(-kv));   // sigmoid(k)
                float g = (th >= 0.0f) ? (th + 0.5f)
                                       : (1.0f / (1.0f + __expf(-th)));
                size_t o = (size_t)bt * Hq + h;
                Cc[o] = c;
                Vv[o] = z * g;
            }
        }
    }
}

// ---------------- chunked linear scan: pass 1 (per-chunk partials) ----------------
__global__ void scan_partials(const float* __restrict__ Cc, const float* __restrict__ Vv,
                              float* __restrict__ chA, float* __restrict__ chW) {
    int h = blockIdx.y * 256 + threadIdx.x;
    int b = blockIdx.x / NC;
    int chunk = blockIdx.x % NC;
    size_t base = ((size_t)b * Tq + (size_t)chunk * CL) * Hq + h;
    float A = 1.0f, W = 0.0f;
    for (int t = 0; t < CL; ++t) {
        float c = Cc[base + (size_t)t * Hq];
        float v = Vv[base + (size_t)t * Hq];
        W = fmaf(c, W, v);
        A *= c;
    }
    size_t o = ((size_t)b * NC + chunk) * Hq + h;
    chA[o] = A;
    chW[o] = W;
}

// ---------------- pass 2: sequential combine over chunks ----------------
__global__ void scan_combine(const float* __restrict__ h0,
                             const float* __restrict__ chA, const float* __restrict__ chW,
                             float* __restrict__ hstart) {
    int idx = blockIdx.x * 256 + threadIdx.x;  // b*H + h
    int b = idx >> 9;
    int h = idx & (Hq - 1);
    float x0 = h0[idx];
    float hr = (x0 >= 0.0f) ? (x0 + 0.5f) : (1.0f / (1.0f + __expf(-x0)));  // g(h_0)
    for (int c = 0; c < NC; ++c) {
        size_t o = ((size_t)b * NC + c) * Hq + h;
        hstart[o] = hr;
        hr = fmaf(chA[o], hr, chW[o]);
    }
}

// ---------------- pass 3: replay chunk with true prefix, write h ----------------
// NOTE: Vv aliases out (same addresses). Each element is read then overwritten by
// the SAME thread (dataflow-ordered), no cross-thread sharing. No __restrict__ here.
__global__ void scan_final(const float* Cc, const float* Vv,
                           const float* hstart, float* out) {
    int h = blockIdx.y * 256 + threadIdx.x;
    int b = blockIdx.x / NC;
    int chunk = blockIdx.x % NC;
    float hr = hstart[((size_t)b * NC + chunk) * Hq + h];
    size_t base = ((size_t)b * Tq + (size_t)chunk * CL) * Hq + h;
    for (int t = 0; t < CL; ++t) {
        size_t o = base + (size_t)t * Hq;
        float c = Cc[o];
        float v = Vv[o];
        hr = fmaf(c, hr, v);
        out[o] = hr;
    }
}

extern "C" void kernel_launch(void* const* d_in, const int* in_sizes, int n_in,
                              void* d_out, int out_size, void* d_ws, size_t ws_size,
                              hipStream_t stream) {
    const float* x  = (const float*)d_in[0];
    const float* h0 = (const float*)d_in[1];
    const float* Wz = (const float*)d_in[2];
    const float* bz = (const float*)d_in[3];
    const float* Wh = (const float*)d_in[4];
    const float* bh = (const float*)d_in[5];
    float* out = (float*)d_out;

    // workspace layout (needs ~68 MB):
    //   Cc       : Mq*Hq fp32            (64 MB)
    //   Wzb,Whb  : 2 * Hq*Dq bf16        ( 1 MB)
    //   chA,chW  : 2 * Bq*NC*Hq fp32     ( 2 MB)
    //   hstart   : Bq*NC*Hq fp32         ( 1 MB)
    char* ws = (char*)d_ws;
    float* Cc = (float*)ws;
    unsigned short* Wzb = (unsigned short*)(ws + (size_t)Mq * Hq * sizeof(float));
    unsigned short* Whb = Wzb + (size_t)Hq * Dq;
    char* p = (char*)(Whb + (size_t)Hq * Dq);
    float* chA = (float*)p;
    float* chW = chA + (size_t)Bq * NC * Hq;
    float* hstart = chW + (size_t)Bq * NC * Hq;
    float* Vv = out;  // v = z*g lives in d_out; scan_final overwrites in place

    convert_weights<<<dim3((2 * Dq * Hq) / (256 * 8)), dim3(256), 0, stream>>>(Wz, Wh, Wzb);
    gemm_fused<<<dim3(Mq / 128, Hq / 128), dim3(256), 0, stream>>>(x, Wzb, Whb, bz, bh, Cc, Vv);
    scan_partials<<<dim3(Bq * NC, Hq / 256), dim3(256), 0, stream>>>(Cc, Vv, chA, chW);
    scan_combine<<<dim3((Bq * Hq) / 256), dim3(256), 0, stream>>>(h0, chA, chW, hstart);
    scan_final<<<dim3(Bq * NC, Hq / 256), dim3(256), 0, stream>>>(Cc, Vv, hstart, out);
}

// Round 2
// 218.585 us; speedup vs baseline: 1.1205x; 1.1205x over previous
//
#include <hip/hip_runtime.h>
#include <math.h>

#define Bq 8
#define Tq 4096
#define Dq 512
#define Hq 512
#define Mq (Bq * Tq)   // 32768
#define NC 64          // chunks along T
#define CL 64          // chunk length

typedef unsigned short ushort_t;
typedef unsigned int uint_t;
typedef __bf16 bf16x8 __attribute__((ext_vector_type(8)));
typedef float f32x4 __attribute__((ext_vector_type(4)));

__device__ __forceinline__ ushort_t f2bf(float f) {
    unsigned int u = __float_as_uint(f);
    unsigned int r = u + 0x7fffu + ((u >> 16) & 1u);
    return (ushort_t)(r >> 16);
}

// async global -> LDS, 16 bytes/lane; lds dest must be wave-uniform base (+lane*16 by HW)
__device__ __forceinline__ void gload16(const void* g, void* l) {
    __builtin_amdgcn_global_load_lds(
        (const __attribute__((address_space(1))) void*)g,
        (__attribute__((address_space(3))) void*)l, 16, 0, 0);
}

// shared gate math: word = bf16(k) | bf16(th)<<16 -> c = 1-sigmoid(k), v = sigmoid(k)*g(th)
__device__ __forceinline__ void gates(uint_t w, float& c, float& v) {
    float k  = __uint_as_float((w & 0xffffu) << 16);
    float th = __uint_as_float(w & 0xffff0000u);
    float ek = __expf(k);
    c = 1.0f / (1.0f + ek);        // 1 - sigmoid(k)
    float z = 1.0f - c;            // sigmoid(k)
    float g = (th >= 0.0f) ? (th + 0.5f) : (1.0f / (1.0f + __expf(-th)));
    v = z * g;
}

// ---------------- convert x, Wz, Wh to bf16 (single pass) ----------------
__global__ __launch_bounds__(256)
void convert_all(const float* __restrict__ x, const float* __restrict__ Wz,
                 const float* __restrict__ Wh, ushort_t* __restrict__ dst) {
    size_t i8 = ((size_t)blockIdx.x * 256 + threadIdx.x) * 8;
    const size_t XN = (size_t)Mq * Dq;        // 16777216
    const size_t WN = (size_t)Hq * Dq;        // 262144
    const float* src; size_t off;
    if (i8 < XN)            { src = x;  off = i8; }
    else if (i8 < XN + WN)  { src = Wz; off = i8 - XN; }
    else                    { src = Wh; off = i8 - XN - WN; }
    float4 a = *reinterpret_cast<const float4*>(src + off);
    float4 b = *reinterpret_cast<const float4*>(src + off + 4);
    uint4 o;
    o.x = (uint_t)f2bf(a.x) | ((uint_t)f2bf(a.y) << 16);
    o.y = (uint_t)f2bf(a.z) | ((uint_t)f2bf(a.w) << 16);
    o.z = (uint_t)f2bf(b.x) | ((uint_t)f2bf(b.y) << 16);
    o.w = (uint_t)f2bf(b.z) | ((uint_t)f2bf(b.w) << 16);
    *reinterpret_cast<uint4*>(dst + i8) = o;
}

// ---------------- fused dual GEMM, m97-style staging + XOR swizzle ----------------
// writes packed word: bf16(k = x.Wz^T + bz) | bf16(th = x.Wh^T + bh)<<16
__global__ __launch_bounds__(256, 2)
void gemm_fused(const ushort_t* __restrict__ xb, const ushort_t* __restrict__ wb,
                const float* __restrict__ bz, const float* __restrict__ bh,
                uint_t* __restrict__ kvout) {
    __shared__ __align__(16) ushort_t As [128 * 64];
    __shared__ __align__(16) ushort_t Bzs[128 * 64];
    __shared__ __align__(16) ushort_t Bhs[128 * 64];

    const int tid  = threadIdx.x;
    const int lane = tid & 63;
    const int wave = tid >> 6;
    const int wm = (wave >> 1) * 64;
    const int wn = (wave & 1) * 64;
    const int mBase = blockIdx.x * 128;
    const int nBase = blockIdx.y * 128;
    const ushort_t* Wzb = wb;
    const ushort_t* Whb = wb + (size_t)Hq * Dq;

    f32x4 zero = {0.f, 0.f, 0.f, 0.f};
    f32x4 accz[4][4], acch[4][4];
#pragma unroll
    for (int i = 0; i < 4; ++i)
#pragma unroll
        for (int j = 0; j < 4; ++j) { accz[i][j] = zero; acch[i][j] = zero; }

    // staging geometry: wave segment rseg=j*4+wave covers rows rseg*8 .. rseg*8+7
    // lane -> row = rseg*8 + (lane>>3), lds chunk pos = lane&7,
    // global chunk = (lane&7) ^ (lane>>3)   [xor swizzle, row&7 == lane>>3]
    const int rowInW = lane >> 3;
    const int ccG = (lane & 7) ^ rowInW;
    const int swz = lane & 7;          // read-side swizzle factor (row&7 == lane&7)

    for (int k0 = 0; k0 < Dq; k0 += 64) {
#pragma unroll
        for (int j = 0; j < 4; ++j) {
            const int rseg = j * 4 + wave;           // 0..15, wave-uniform
            const int row  = rseg * 8 + rowInW;      // 0..127
            const size_t gcol = (size_t)(k0 + ccG * 8);
            gload16(xb  + (size_t)(mBase + row) * Dq + gcol, &As [rseg * 512]);
            gload16(Wzb + (size_t)(nBase + row) * Dq + gcol, &Bzs[rseg * 512]);
            gload16(Whb + (size_t)(nBase + row) * Dq + gcol, &Bhs[rseg * 512]);
        }
        __syncthreads();

#pragma unroll
        for (int ks = 0; ks < 2; ++ks) {
            const int cc = ks * 4 + (lane >> 4);     // k chunk 0..7
            const int sc = cc ^ swz;                 // swizzled lds chunk
            bf16x8 af[4], bzf[4], bhf[4];
#pragma unroll
            for (int i = 0; i < 4; ++i) {
                int rowA = wm + i * 16 + (lane & 15);
                af[i] = *reinterpret_cast<const bf16x8*>(&As[rowA * 64 + sc * 8]);
            }
#pragma unroll
            for (int i = 0; i < 4; ++i) {
                int rowB = wn + i * 16 + (lane & 15);
                bzf[i] = *reinterpret_cast<const bf16x8*>(&Bzs[rowB * 64 + sc * 8]);
                bhf[i] = *reinterpret_cast<const bf16x8*>(&Bhs[rowB * 64 + sc * 8]);
            }
#pragma unroll
            for (int mi = 0; mi < 4; ++mi)
#pragma unroll
                for (int ni = 0; ni < 4; ++ni) {
                    accz[mi][ni] = __builtin_amdgcn_mfma_f32_16x16x32_bf16(
                        af[mi], bzf[ni], accz[mi][ni], 0, 0, 0);
                    acch[mi][ni] = __builtin_amdgcn_mfma_f32_16x16x32_bf16(
                        af[mi], bhf[ni], acch[mi][ni], 0, 0, 0);
                }
        }
        __syncthreads();
    }

    // epilogue: C/D layout col=lane&15, row=(lane>>4)*4+reg
    const int colL = lane & 15;
    const int rowQ = (lane >> 4) * 4;
#pragma unroll
    for (int mi = 0; mi < 4; ++mi) {
#pragma unroll
        for (int ni = 0; ni < 4; ++ni) {
            int h = nBase + wn + ni * 16 + colL;
            float bzv = bz[h];
            float bhv = bh[h];
#pragma unroll
            for (int r = 0; r < 4; ++r) {
                int bt = mBase + wm + mi * 16 + rowQ + r;
                float kf  = accz[mi][ni][r] + bzv;
                float thf = acch[mi][ni][r] + bhv;
                kvout[(size_t)bt * Hq + h] =
                    (uint_t)f2bf(kf) | ((uint_t)f2bf(thf) << 16);
            }
        }
    }
}

// ---------------- pass 1: per-chunk affine partials (2 h per thread) ----------------
__global__ __launch_bounds__(256)
void scan_partials(const uint_t* __restrict__ kv, float4* __restrict__ chAW) {
    const int b = blockIdx.x >> 6;
    const int chunk = blockIdx.x & 63;
    const int h2 = threadIdx.x;                    // 0..255 over H/2 pairs
    const uint2* kv2 = reinterpret_cast<const uint2*>(kv);
    size_t base = ((size_t)b * Tq + (size_t)chunk * CL) * (Hq / 2) + h2;
    float A0 = 1.f, W0 = 0.f, A1 = 1.f, W1 = 0.f;
#pragma unroll 8
    for (int t = 0; t < CL; ++t) {
        uint2 w = kv2[base + (size_t)t * (Hq / 2)];
        float c0, v0, c1, v1;
        gates(w.x, c0, v0);
        gates(w.y, c1, v1);
        W0 = fmaf(c0, W0, v0); A0 *= c0;
        W1 = fmaf(c1, W1, v1); A1 *= c1;
    }
    chAW[(size_t)blockIdx.x * (Hq / 2) + h2] = make_float4(A0, W0, A1, W1);
}

// ---------------- pass 2: sequential combine over chunks ----------------
__global__ __launch_bounds__(256)
void scan_combine(const float* __restrict__ h0, const float4* __restrict__ chAW,
                  float2* __restrict__ hstart) {
    int idx = blockIdx.x * 256 + threadIdx.x;      // b*(H/2) + h2, 0..2047
    float2 x0 = reinterpret_cast<const float2*>(h0)[idx];
    int b = idx >> 8;
    int h2 = idx & 255;
    float r0 = (x0.x >= 0.f) ? (x0.x + 0.5f) : (1.f / (1.f + __expf(-x0.x)));
    float r1 = (x0.y >= 0.f) ? (x0.y + 0.5f) : (1.f / (1.f + __expf(-x0.y)));
    for (int c = 0; c < NC; ++c) {
        size_t o = ((size_t)b * NC + c) * (Hq / 2) + h2;
        hstart[o] = make_float2(r0, r1);
        float4 aw = chAW[o];
        r0 = fmaf(aw.x, r0, aw.y);
        r1 = fmaf(aw.z, r1, aw.w);
    }
}

// ---------------- pass 3: replay with true prefix, write h ----------------
// kv aliases out (same buffer). Explicit 8-deep batch prefetch keeps loads ahead
// of the may-aliasing stores (each address is read before it is written, and only
// by the same thread).
__global__ __launch_bounds__(256)
void scan_final(const uint_t* kv, const float2* __restrict__ hstart, float* out) {
    const int b = blockIdx.x >> 6;
    const int chunk = blockIdx.x & 63;
    const int h2 = threadIdx.x;
    float2 hs = hstart[(size_t)blockIdx.x * (Hq / 2) + h2];
    float r0 = hs.x, r1 = hs.y;
    const uint2* kv2 = reinterpret_cast<const uint2*>(kv);
    float2* out2 = reinterpret_cast<float2*>(out);
    size_t base = ((size_t)b * Tq + (size_t)chunk * CL) * (Hq / 2) + h2;

    uint2 w[8];
#pragma unroll
    for (int j = 0; j < 8; ++j) w[j] = kv2[base + (size_t)j * (Hq / 2)];

    for (int bt = 0; bt < 8; ++bt) {
        uint2 wn[8];
        if (bt < 7) {
#pragma unroll
            for (int j = 0; j < 8; ++j)
                wn[j] = kv2[base + (size_t)((bt + 1) * 8 + j) * (Hq / 2)];
        }
#pragma unroll
        for (int j = 0; j < 8; ++j) {
            float c0, v0, c1, v1;
            gates(w[j].x, c0, v0);
            gates(w[j].y, c1, v1);
            r0 = fmaf(c0, r0, v0);
            r1 = fmaf(c1, r1, v1);
            out2[base + (size_t)(bt * 8 + j) * (Hq / 2)] = make_float2(r0, r1);
        }
#pragma unroll
        for (int j = 0; j < 8; ++j) w[j] = wn[j];
    }
}

extern "C" void kernel_launch(void* const* d_in, const int* in_sizes, int n_in,
                              void* d_out, int out_size, void* d_ws, size_t ws_size,
                              hipStream_t stream) {
    const float* x  = (const float*)d_in[0];
    const float* h0 = (const float*)d_in[1];
    const float* Wz = (const float*)d_in[2];
    const float* bz = (const float*)d_in[3];
    const float* Wh = (const float*)d_in[4];
    const float* bh = (const float*)d_in[5];
    float* out = (float*)d_out;

    // ws layout (~36.5 MB):
    //   xb   : Mq*Dq bf16                (32 MB)
    //   wb   : 2*Hq*Dq bf16 (Wz||Wh)     ( 1 MB)
    //   chAW : Bq*NC*(Hq/2) float4       ( 2 MB)
    //   hstart: Bq*NC*(Hq/2) float2      ( 1 MB)
    char* ws = (char*)d_ws;
    ushort_t* xb = (ushort_t*)ws;
    ushort_t* wb = xb + (size_t)Mq * Dq;
    float4* chAW = (float4*)(wb + 2 * (size_t)Hq * Dq);
    float2* hstart = (float2*)((char*)chAW + (size_t)Bq * NC * (Hq / 2) * 16);
    uint_t* kv = (uint_t*)d_out;   // packed (k,th) lives in d_out; scan_final overwrites

    const int totalConv = (Mq * Dq + 2 * Hq * Dq) / (256 * 8);   // 8448 blocks
    convert_all<<<dim3(totalConv), dim3(256), 0, stream>>>(x, Wz, Wh, xb);
    gemm_fused<<<dim3(Mq / 128, Hq / 128), dim3(256), 0, stream>>>(xb, wb, bz, bh, kv);
    scan_partials<<<dim3(Bq * NC), dim3(256), 0, stream>>>(kv, chAW);
    scan_combine<<<dim3(Bq), dim3(256), 0, stream>>>(h0, chAW, hstart);
    scan_final<<<dim3(Bq * NC), dim3(256), 0, stream>>>(kv, hstart, out);
}

// Round 3
// 199.688 us; speedup vs baseline: 1.2265x; 1.0946x over previous
//
#include <hip/hip_runtime.h>
#include <math.h>

#define Bq 8
#define Tq 4096
#define Dq 512
#define Hq 512
#define Mq (Bq * Tq)   // 32768
#define NC 64          // chunks along T
#define CL 64          // chunk length

typedef unsigned short ushort_t;
typedef unsigned int uint_t;
typedef __bf16 bf16x8 __attribute__((ext_vector_type(8)));
typedef float f32x4 __attribute__((ext_vector_type(4)));

__device__ __forceinline__ ushort_t f2bf(float f) {
    unsigned int u = __float_as_uint(f);
    unsigned int r = u + 0x7fffu + ((u >> 16) & 1u);
    return (ushort_t)(r >> 16);
}

// async global -> LDS, 16 bytes/lane; lds dest is wave-uniform base (+lane*16 by HW)
__device__ __forceinline__ void gload16(const void* g, void* l) {
    __builtin_amdgcn_global_load_lds(
        (const __attribute__((address_space(1))) void*)g,
        (__attribute__((address_space(3))) void*)l, 16, 0, 0);
}

// word = bf16(k) | bf16(th)<<16 -> c = 1-sigmoid(k), v = sigmoid(k)*g(th)
__device__ __forceinline__ void gates(uint_t w, float& c, float& v) {
    float k  = __uint_as_float((w & 0xffffu) << 16);
    float th = __uint_as_float(w & 0xffff0000u);
    float ek = __expf(k);
    c = 1.0f / (1.0f + ek);        // 1 - sigmoid(k)
    float z = 1.0f - c;            // sigmoid(k)
    float g = (th >= 0.0f) ? (th + 0.5f) : (1.0f / (1.0f + __expf(-th)));
    v = z * g;
}

// ---------------- convert x, Wz, Wh to bf16 (single pass) ----------------
__global__ __launch_bounds__(256)
void convert_all(const float* __restrict__ x, const float* __restrict__ Wz,
                 const float* __restrict__ Wh, ushort_t* __restrict__ dst) {
    size_t i8 = ((size_t)blockIdx.x * 256 + threadIdx.x) * 8;
    const size_t XN = (size_t)Mq * Dq;
    const size_t WN = (size_t)Hq * Dq;
    const float* src; size_t off;
    if (i8 < XN)            { src = x;  off = i8; }
    else if (i8 < XN + WN)  { src = Wz; off = i8 - XN; }
    else                    { src = Wh; off = i8 - XN - WN; }
    float4 a = *reinterpret_cast<const float4*>(src + off);
    float4 b = *reinterpret_cast<const float4*>(src + off + 4);
    uint4 o;
    o.x = (uint_t)f2bf(a.x) | ((uint_t)f2bf(a.y) << 16);
    o.y = (uint_t)f2bf(a.z) | ((uint_t)f2bf(a.w) << 16);
    o.z = (uint_t)f2bf(b.x) | ((uint_t)f2bf(b.y) << 16);
    o.w = (uint_t)f2bf(b.z) | ((uint_t)f2bf(b.w) << 16);
    *reinterpret_cast<uint4*>(dst + i8) = o;
}

// ---------------- fused dual GEMM + gates + per-chunk scan partials ----------------
__global__ __launch_bounds__(256, 2)
void gemm_fused(const ushort_t* __restrict__ xb, const ushort_t* __restrict__ wb,
                const float* __restrict__ bz, const float* __restrict__ bh,
                uint_t* __restrict__ kvout, float2* __restrict__ chAW) {
    __shared__ __align__(16) ushort_t smem[3 * 128 * 64];   // 48 KB
    ushort_t* As  = smem;
    ushort_t* Bzs = smem + 128 * 64;
    ushort_t* Bhs = smem + 2 * 128 * 64;

    const int tid  = threadIdx.x;
    const int lane = tid & 63;
    const int wave = tid >> 6;
    const int wm = (wave >> 1) * 64;
    const int wn = (wave & 1) * 64;
    const int mBase = blockIdx.x * 128;
    const int nBase = blockIdx.y * 128;
    const ushort_t* Wzb = wb;
    const ushort_t* Whb = wb + (size_t)Hq * Dq;

    f32x4 zero = {0.f, 0.f, 0.f, 0.f};
    f32x4 accz[4][4], acch[4][4];
#pragma unroll
    for (int i = 0; i < 4; ++i)
#pragma unroll
        for (int j = 0; j < 4; ++j) { accz[i][j] = zero; acch[i][j] = zero; }

    const int rowInW = lane >> 3;
    const int ccG = (lane & 7) ^ rowInW;   // xor-swizzled global chunk
    const int swz = lane & 7;              // read-side swizzle

    for (int k0 = 0; k0 < Dq; k0 += 64) {
#pragma unroll
        for (int j = 0; j < 4; ++j) {
            const int rseg = j * 4 + wave;
            const int row  = rseg * 8 + rowInW;
            const size_t gcol = (size_t)(k0 + ccG * 8);
            gload16(xb  + (size_t)(mBase + row) * Dq + gcol, &As [rseg * 512]);
            gload16(Wzb + (size_t)(nBase + row) * Dq + gcol, &Bzs[rseg * 512]);
            gload16(Whb + (size_t)(nBase + row) * Dq + gcol, &Bhs[rseg * 512]);
        }
        __syncthreads();

#pragma unroll
        for (int ks = 0; ks < 2; ++ks) {
            const int cc = ks * 4 + (lane >> 4);
            const int sc = cc ^ swz;
            bf16x8 af[4], bzf[4], bhf[4];
#pragma unroll
            for (int i = 0; i < 4; ++i) {
                int rowA = wm + i * 16 + (lane & 15);
                af[i] = *reinterpret_cast<const bf16x8*>(&As[rowA * 64 + sc * 8]);
            }
#pragma unroll
            for (int i = 0; i < 4; ++i) {
                int rowB = wn + i * 16 + (lane & 15);
                bzf[i] = *reinterpret_cast<const bf16x8*>(&Bzs[rowB * 64 + sc * 8]);
                bhf[i] = *reinterpret_cast<const bf16x8*>(&Bhs[rowB * 64 + sc * 8]);
            }
#pragma unroll
            for (int mi = 0; mi < 4; ++mi)
#pragma unroll
                for (int ni = 0; ni < 4; ++ni) {
                    accz[mi][ni] = __builtin_amdgcn_mfma_f32_16x16x32_bf16(
                        af[mi], bzf[ni], accz[mi][ni], 0, 0, 0);
                    acch[mi][ni] = __builtin_amdgcn_mfma_f32_16x16x32_bf16(
                        af[mi], bhf[ni], acch[mi][ni], 0, 0, 0);
                }
        }
        __syncthreads();
    }

    // ---- epilogue: write packed kv AND per-chunk affine partials ----
    // C/D layout: col = lane&15, row = (lane>>4)*4 + r. Wave quadrant covers
    // exactly one T-chunk (rows wm..wm+63 of a 128-row tile; 64 == CL).
    const int colL = lane & 15;
    const int quad = lane >> 4;
    float2* sb = reinterpret_cast<float2*>(smem) + wave * 1024;  // [16 seg][64 col]

#pragma unroll
    for (int ni = 0; ni < 4; ++ni) {
        int h = nBase + wn + ni * 16 + colL;
        float bzv = bz[h];
        float bhv = bh[h];
#pragma unroll
        for (int mi = 0; mi < 4; ++mi) {
            float A = 1.f, W = 0.f;
#pragma unroll
            for (int r = 0; r < 4; ++r) {
                int bt = mBase + wm + mi * 16 + quad * 4 + r;
                float kf  = accz[mi][ni][r] + bzv;
                float thf = acch[mi][ni][r] + bhv;
                uint_t word = (uint_t)f2bf(kf) | ((uint_t)f2bf(thf) << 16);
                kvout[(size_t)bt * Hq + h] = word;
                float c, v;
                gates(word, c, v);           // from ROUNDED values: matches replay
                W = fmaf(c, W, v);
                A *= c;
            }
            sb[(mi * 4 + quad) * 64 + ni * 16 + colL] = make_float2(A, W);
        }
    }
    __syncthreads();
    {
        float A = 1.f, W = 0.f;
#pragma unroll
        for (int s = 0; s < 16; ++s) {       // seg = mi*4 + quad: increasing t
            float2 aw = sb[s * 64 + lane];
            W = fmaf(aw.x, W, aw.y);
            A *= aw.x;
        }
        int g = blockIdx.x * 2 + (wm >> 6);  // global chunk id = b*NC + chunk
        int h = nBase + wn + lane;
        chAW[(size_t)g * Hq + h] = make_float2(A, W);
    }
}

// ---------------- sequential combine over chunks (batched prefetch) ----------------
__global__ __launch_bounds__(256)
void scan_combine(const float* __restrict__ h0, const float2* __restrict__ chAW,
                  float* __restrict__ hstart) {
    int idx = blockIdx.x * 256 + threadIdx.x;  // b*H + h, 0..4095
    int b = idx >> 9;
    int h = idx & (Hq - 1);
    float x0 = h0[idx];
    float r = (x0 >= 0.f) ? (x0 + 0.5f) : (1.f / (1.f + __expf(-x0)));
    const float2* p = chAW + (size_t)b * NC * Hq + h;
    for (int c0 = 0; c0 < NC; c0 += 16) {
        float2 aw[16];
#pragma unroll
        for (int j = 0; j < 16; ++j) aw[j] = p[(size_t)(c0 + j) * Hq];
#pragma unroll
        for (int j = 0; j < 16; ++j) {
            hstart[((size_t)b * NC + c0 + j) * Hq + h] = r;
            r = fmaf(aw[j].x, r, aw[j].y);
        }
    }
}

// ---------------- replay with true prefix, write h ----------------
// kv aliases out; each address read before written by the SAME thread.
__global__ __launch_bounds__(256)
void scan_final(const uint_t* kv, const float* __restrict__ hstart, float* out) {
    const int b = blockIdx.x >> 6;
    const int chunk = blockIdx.x & 63;
    const int h2 = threadIdx.x;
    float2 hs = reinterpret_cast<const float2*>(hstart)[(size_t)blockIdx.x * (Hq / 2) + h2];
    float r0 = hs.x, r1 = hs.y;
    const uint2* kv2 = reinterpret_cast<const uint2*>(kv);
    float2* out2 = reinterpret_cast<float2*>(out);
    size_t base = ((size_t)b * Tq + (size_t)chunk * CL) * (Hq / 2) + h2;

    uint2 w[8];
#pragma unroll
    for (int j = 0; j < 8; ++j) w[j] = kv2[base + (size_t)j * (Hq / 2)];

    for (int bt = 0; bt < 8; ++bt) {
        uint2 wn[8];
        if (bt < 7) {
#pragma unroll
            for (int j = 0; j < 8; ++j)
                wn[j] = kv2[base + (size_t)((bt + 1) * 8 + j) * (Hq / 2)];
        }
#pragma unroll
        for (int j = 0; j < 8; ++j) {
            float c0, v0, c1, v1;
            gates(w[j].x, c0, v0);
            gates(w[j].y, c1, v1);
            r0 = fmaf(c0, r0, v0);
            r1 = fmaf(c1, r1, v1);
            out2[base + (size_t)(bt * 8 + j) * (Hq / 2)] = make_float2(r0, r1);
        }
#pragma unroll
        for (int j = 0; j < 8; ++j) w[j] = wn[j];
    }
}

extern "C" void kernel_launch(void* const* d_in, const int* in_sizes, int n_in,
                              void* d_out, int out_size, void* d_ws, size_t ws_size,
                              hipStream_t stream) {
    const float* x  = (const float*)d_in[0];
    const float* h0 = (const float*)d_in[1];
    const float* Wz = (const float*)d_in[2];
    const float* bz = (const float*)d_in[3];
    const float* Wh = (const float*)d_in[4];
    const float* bh = (const float*)d_in[5];
    float* out = (float*)d_out;

    // ws layout (~36 MB): xb 32MB | wb 1MB | chAW 2MB | hstart 1MB
    char* ws = (char*)d_ws;
    ushort_t* xb = (ushort_t*)ws;
    ushort_t* wb = xb + (size_t)Mq * Dq;
    float2* chAW = (float2*)(wb + 2 * (size_t)Hq * Dq);
    float* hstart = (float*)((char*)chAW + (size_t)Bq * NC * Hq * sizeof(float2));
    uint_t* kv = (uint_t*)d_out;

    const int totalConv = (Mq * Dq + 2 * Hq * Dq) / (256 * 8);
    convert_all<<<dim3(totalConv), dim3(256), 0, stream>>>(x, Wz, Wh, xb);
    gemm_fused<<<dim3(Mq / 128, Hq / 128), dim3(256), 0, stream>>>(xb, wb, bz, bh, kv, chAW);
    scan_combine<<<dim3((Bq * Hq) / 256), dim3(256), 0, stream>>>(h0, chAW, hstart);
    scan_final<<<dim3(Bq * NC), dim3(256), 0, stream>>>(kv, hstart, out);
}